// Round 2
// baseline (12776.233 us; speedup 1.0000x reference)
//
#include <hip/hip_runtime.h>

#define SLOTS 64          // per-node accumulator: s1[15] s2[15] s3[15] s4[15] count pad3 (256 B)
#define NN    32          // nodes per block in node_kernel

__device__ __forceinline__ float leaky(float x) { return fmaxf(x, 0.1f * x); }

// ---------------- K1: dense edge pass — MLP + global-atomic moment accumulation ----------------
__global__ __launch_bounds__(256) void edge_kernel(
    const int* __restrict__ edge_index, const float* __restrict__ x_t,
    const float* __restrict__ edge_attr,
    const float* __restrict__ w1a, const float* __restrict__ b1a,
    const float* __restrict__ w2a, const float* __restrict__ b2a,
    float* __restrict__ accs, int E)
{
    __shared__ float sw1[240], sw2[240], sb1[16], sb2[16];
    int tid = threadIdx.x;

    for (int i = tid; i < 240; i += 256) {
        int r = i >> 4, c = i & 15;
        sw1[i] = (c < 15) ? w1a[r * 15 + c] : 0.f;
        sw2[i] = (c < 15) ? w2a[r * 15 + c] : 0.f;
    }
    if (tid < 15) { sb1[tid] = b1a[tid]; sb2[tid] = b2a[tid]; }
    __syncthreads();

    int stride = gridDim.x * 256;
    for (int i = blockIdx.x * 256 + tid; i < E; i += stride) {
        int s = edge_index[i];
        int t = edge_index[E + i];

        float in0[15];
        const float* xt = x_t + (size_t)t * 5;
#pragma unroll
        for (int q = 0; q < 5; q++) in0[q] = xt[q];
        const float2* ea = (const float2*)(edge_attr + (size_t)i * 10);
#pragma unroll
        for (int q = 0; q < 5; q++) { float2 t2 = ea[q]; in0[5 + 2 * q] = t2.x; in0[6 + 2 * q] = t2.y; }

        float h[15];
#pragma unroll
        for (int j = 0; j < 15; j++) h[j] = sb1[j];
#pragma unroll
        for (int ii = 0; ii < 15; ii++)
#pragma unroll
            for (int j = 0; j < 15; j++) h[j] = fmaf(in0[ii], sw1[ii * 16 + j], h[j]);
#pragma unroll
        for (int j = 0; j < 15; j++) h[j] = leaky(h[j]);

        float y[15];
#pragma unroll
        for (int j = 0; j < 15; j++) y[j] = sb2[j];
#pragma unroll
        for (int ii = 0; ii < 15; ii++)
#pragma unroll
            for (int j = 0; j < 15; j++) y[j] = fmaf(h[ii], sw2[ii * 16 + j], y[j]);

        float* ab = accs + (size_t)s * SLOTS;
#pragma unroll
        for (int j = 0; j < 15; j++) {
            float yv = y[j], y2 = yv * yv;
            unsafeAtomicAdd(ab + j,      yv);
            unsafeAtomicAdd(ab + 15 + j, y2);
            unsafeAtomicAdd(ab + 30 + j, y2 * yv);
            unsafeAtomicAdd(ab + 45 + j, y2 * y2);
        }
        unsafeAtomicAdd(ab + 60, 1.0f);
    }
}

// ---------------- K2: per-node finalize + node MLP ----------------
__global__ __launch_bounds__(256) void node_kernel(
    const float* __restrict__ accs,
    const float* __restrict__ x_s, const float* __restrict__ u,
    const int* __restrict__ batch_s,
    const float* __restrict__ w1b, const float* __restrict__ b1b,
    const float* __restrict__ w2b, const float* __restrict__ b2b,
    float* __restrict__ out, int N)
{
    __shared__ float tw1[810], tw2[100], tb1[16], tb2[16];
    __shared__ float harr[NN * 81];
    __shared__ float o1s[NN * 10];
    int tid = threadIdx.x;

    for (int i = tid; i < 810; i += 256) tw1[i] = w1b[i];
    for (int i = tid; i < 100; i += 256) tw2[i] = w2b[i];
    if (tid < 10) { tb1[tid] = b1b[tid]; tb2[tid] = b2b[tid]; }

    int n0 = blockIdx.x * NN;
    int nn = min(NN, N - n0);
    __syncthreads();

    // finalize raw sums -> mean/std/skew/kurt, drop into harr
    for (int idx = tid; idx < nn * 16; idx += 256) {
        int nd = idx >> 4, f = idx & 15;
        const float* ab = accs + (size_t)(n0 + nd) * SLOTS;
        float cf = ab[60];
        if (f < 15) {
            float inv = 1.0f / fmaxf(cf, 1.0f);
            float m1 = ab[f]      * inv;
            float m2 = ab[15 + f] * inv;
            float m3 = ab[30 + f] * inv;
            float m4 = ab[45 + f] * inv;
            float var = fmaxf(m2 - m1 * m1, 0.0f);
            float sd  = sqrtf(var + 1e-6f);
            float m1sq = m1 * m1;
            float c3 = m3 - 3.0f * m1 * m2 + 2.0f * m1sq * m1;
            float c4 = m4 - 4.0f * m1 * m3 + 6.0f * m1sq * m2 - 3.0f * m1sq * m1sq;
            float is = 1.0f / sd, is2 = is * is;
            harr[nd * 81 + 11 + f] = m1;
            harr[nd * 81 + 26 + f] = sd;
            harr[nd * 81 + 41 + f] = c3 * is2 * is;
            harr[nd * 81 + 56 + f] = c4 * is2 * is2;
        } else {
            harr[nd * 81 + 10] = cf;
        }
    }
    for (int idx = tid; idx < nn * 10; idx += 256) {
        int nd = idx / 10, q = idx - nd * 10;
        harr[nd * 81 + q]      = x_s[(size_t)(n0 + nd) * 10 + q];
        harr[nd * 81 + 71 + q] = u[(size_t)batch_s[n0 + nd] * 10 + q];
    }
    __syncthreads();

    // node MLP: 81 -> 10 (leaky) -> 10
    for (int idx = tid; idx < nn * 10; idx += 256) {
        int nd = idx / 10, k = idx - nd * 10;
        float a = tb1[k];
#pragma unroll
        for (int j = 0; j < 81; j++) a = fmaf(harr[nd * 81 + j], tw1[j * 10 + k], a);
        o1s[idx] = leaky(a);
    }
    __syncthreads();
    for (int idx = tid; idx < nn * 10; idx += 256) {
        int nd = idx / 10, k = idx - nd * 10;
        float a = tb2[k];
#pragma unroll
        for (int m = 0; m < 10; m++) a = fmaf(o1s[nd * 10 + m], tw2[m * 10 + k], a);
        out[(size_t)(n0 + nd) * 10 + k] = a;
    }
}

extern "C" void kernel_launch(void* const* d_in, const int* in_sizes, int n_in,
                              void* d_out, int out_size, void* d_ws, size_t ws_size,
                              hipStream_t stream)
{
    const float* x_s       = (const float*)d_in[0];
    const float* x_t       = (const float*)d_in[1];
    const float* edge_attr = (const float*)d_in[2];
    const float* u         = (const float*)d_in[3];
    const int*   edge_index= (const int*)d_in[4];
    const int*   batch_s   = (const int*)d_in[5];
    const float* w1a = (const float*)d_in[6];
    const float* b1a = (const float*)d_in[7];
    const float* w2a = (const float*)d_in[8];
    const float* b2a = (const float*)d_in[9];
    const float* w1b = (const float*)d_in[10];
    const float* b1b = (const float*)d_in[11];
    const float* w2b = (const float*)d_in[12];
    const float* b2b = (const float*)d_in[13];

    int N = in_sizes[0] / 10;   // x_s [N,10]
    int E = in_sizes[2] / 10;   // edge_attr [E,10]

    float* accs = (float*)d_ws;                         // N * 64 floats = 25.6 MB
    hipMemsetAsync(accs, 0, (size_t)N * SLOTS * sizeof(float), stream);

    int eblocks = (E + 255) / 256;
    if (eblocks > 4096) eblocks = 4096;
    edge_kernel<<<eblocks, 256, 0, stream>>>(
        edge_index, x_t, edge_attr, w1a, b1a, w2a, b2a, accs, E);

    node_kernel<<<(N + NN - 1) / NN, 256, 0, stream>>>(
        accs, x_s, u, batch_s, w1b, b1b, w2b, b2b, (float*)d_out, N);
}

// Round 4
// 766.722 us; speedup vs baseline: 16.6634x; 16.6634x over previous
//
#include <hip/hip_runtime.h>
#include <math.h>

#define NBMAX    1024     // max final buckets (N <= 131072)
#define NSUPMAX  32       // max super-buckets
#define C2       1024     // chunk edges for K2/K3 (ys staging = 64 KB)
#define CH4      2048     // chunk edges for K4
#define SLOTS    61       // per-node accumulator slots: s1[15] s2[15] s3[15] s4[15] count

__device__ __forceinline__ float leaky(float x) { return fmaxf(x, 0.1f * x); }

// ---------------- K2: stream-order edge MLP + level-1 radix (by super-bucket) --------
// Reads edge_index/edge_attr coalesced/ascending; stages 64-B payloads in LDS sorted
// by super (<=25), flushes ~2.6 KB runs to A. Payload: y[15] + (src & 4095).
__global__ __launch_bounds__(512, 4) void binmlp_kernel(
    const int* __restrict__ edge_index, const float* __restrict__ x_t,
    const float* __restrict__ edge_attr,
    const float* __restrict__ w1a, const float* __restrict__ b1a,
    const float* __restrict__ w2a, const float* __restrict__ b2a,
    int* __restrict__ acur, float* __restrict__ A,
    int E, int g0s, int g1s, int capS)
{
    __shared__ float ys[C2 * 16];                       // 64 KB
    __shared__ int   s_sp[C2];                          // super (rel) per sorted slot
    __shared__ int   shist[NSUPMAX], sexcl[NSUPMAX], scur[NSUPMAX], sgof[NSUPMAX];
    __shared__ int   s_total;
    __shared__ float sw1[240], sw2[240], sb1[16], sb2[16];
    int tid = threadIdx.x;

    for (int i = tid; i < 240; i += 512) {
        int r = i >> 4, c = i & 15;
        sw1[i] = (c < 15) ? w1a[r * 15 + c] : 0.f;
        sw2[i] = (c < 15) ? w2a[r * 15 + c] : 0.f;
    }
    if (tid < 15) { sb1[tid] = b1a[tid]; sb2[tid] = b2a[tid]; }
    if (tid < NSUPMAX) shist[tid] = 0;

    int cbase = blockIdx.x * C2;
    int n = min(C2, E - cbase);
    __syncthreads();

    // phase A: coalesced metadata load + chunk histogram over supers in sweep
    int msrc[2], mtgt[2], msup[2];
#pragma unroll
    for (int q = 0; q < 2; q++) {
        int i = tid + q * 512;
        msup[q] = -1;
        if (i < n) {
            int s = edge_index[cbase + i];
            int sup = s >> 12;
            if (sup >= g0s && sup < g1s) {
                msrc[q] = s; mtgt[q] = edge_index[E + cbase + i];
                msup[q] = sup - g0s;
                atomicAdd(&shist[sup - g0s], 1);
            }
        }
    }
    __syncthreads();

    // phase B: exclusive scan over <=32 supers (single wave)
    if (tid < 64) {
        int v = (tid < NSUPMAX) ? shist[tid] : 0;
        int inc = v;
#pragma unroll
        for (int d = 1; d < 64; d <<= 1) { int m = __shfl_up(inc, d); if (tid >= d) inc += m; }
        if (tid < NSUPMAX) sexcl[tid] = inc - v;
        if (tid == 63) s_total = inc;
    }
    __syncthreads();

    // phase C: reserve global runs; sgof[su] = global_off - sexcl[su]
    if (tid < NSUPMAX) {
        scur[tid] = sexcl[tid];
        int c = shist[tid];
        if (c) sgof[tid] = atomicAdd(&acur[g0s + tid], c) - sexcl[tid];
    }
    __syncthreads();

    // phase D: MLP + scatter payload into sorted LDS slot
#pragma unroll
    for (int q = 0; q < 2; q++) {
        int su = msup[q];
        if (su >= 0) {
            int i = tid + q * 512;
            int src = msrc[q], tgt = mtgt[q];

            float in0[15];
            const float* xt = x_t + (size_t)tgt * 5;
#pragma unroll
            for (int r = 0; r < 5; r++) in0[r] = xt[r];
            const float2* ea = (const float2*)(edge_attr + (size_t)(cbase + i) * 10);
#pragma unroll
            for (int r = 0; r < 5; r++) { float2 t2 = ea[r]; in0[5 + 2 * r] = t2.x; in0[6 + 2 * r] = t2.y; }

            float h[15];
#pragma unroll
            for (int j = 0; j < 15; j++) h[j] = sb1[j];
#pragma unroll
            for (int ii = 0; ii < 15; ii++)
#pragma unroll
                for (int j = 0; j < 15; j++) h[j] = fmaf(in0[ii], sw1[ii * 16 + j], h[j]);
#pragma unroll
            for (int j = 0; j < 15; j++) h[j] = leaky(h[j]);

            float y[15];
#pragma unroll
            for (int j = 0; j < 15; j++) y[j] = sb2[j];
#pragma unroll
            for (int ii = 0; ii < 15; ii++)
#pragma unroll
                for (int j = 0; j < 15; j++) y[j] = fmaf(h[ii], sw2[ii * 16 + j], y[j]);

            int p = atomicAdd(&scur[su], 1);
            s_sp[p] = su;
            float* yr = &ys[p * 16];
#pragma unroll
            for (int j = 0; j < 15; j++) yr[j] = y[j];
            yr[15] = __int_as_float(src & 4095);
        }
    }
    __syncthreads();

    // phase E: coalesced run flush (A indexed by sweep-relative super)
    int total = s_total;
    for (int i = tid; i < total; i += 512) {
        int su = s_sp[i];
        int o = sgof[su] + i;                  // offset within super region
        if ((unsigned)o < (unsigned)capS) {
            size_t rec = (size_t)su * capS + o;
            float4* dst = (float4*)(A + rec * 16);
            const float4* sp = (const float4*)&ys[i * 16];
            dst[0] = sp[0]; dst[1] = sp[1]; dst[2] = sp[2]; dst[3] = sp[3];
        }
    }
}

// ---------------- K3: level-2 radix (by sub-bucket within super) --------------------
// Reads A sequentially (L3-hot), stages 1024 payloads sorted by sub (32), flushes
// ~2 KB runs to B (contiguous per final 128-node bucket).
__global__ __launch_bounds__(512, 4) void rebin_kernel(
    const float* __restrict__ A, const int* __restrict__ acur,
    int* __restrict__ bcur2, float* __restrict__ B,
    int g0s, int capS, int cps, int capB)
{
    int srel = blockIdx.x / cps;
    int c    = blockIdx.x - srel * cps;
    int s    = g0s + srel;
    int nsup = min(acur[s], capS);
    int off  = c * C2;
    if (off >= nsup) return;                   // uniform exit

    __shared__ float ys[C2 * 16];              // 64 KB
    __shared__ int   s_sb[C2];
    __shared__ int   shist[32], sexcl[32], scur[32], sgof[32];
    int tid = threadIdx.x;
    if (tid < 32) shist[tid] = 0;
    int n = min(C2, nsup - off);
    __syncthreads();

    size_t abase = (size_t)srel * capS + off;
    float4 ra[4], rb[4];
    int sba = -1, sbb = -1;
    if (tid < n) {
        const float4* ap = (const float4*)(A + (abase + tid) * 16);
        ra[0] = ap[0]; ra[1] = ap[1]; ra[2] = ap[2]; ra[3] = ap[3];
        sba = (__float_as_int(ra[3].w) >> 7) & 31;
        atomicAdd(&shist[sba], 1);
    }
    if (tid + 512 < n) {
        const float4* ap = (const float4*)(A + (abase + tid + 512) * 16);
        rb[0] = ap[0]; rb[1] = ap[1]; rb[2] = ap[2]; rb[3] = ap[3];
        sbb = (__float_as_int(rb[3].w) >> 7) & 31;
        atomicAdd(&shist[sbb], 1);
    }
    __syncthreads();

    if (tid < 64) {
        int v = (tid < 32) ? shist[tid] : 0;
        int inc = v;
#pragma unroll
        for (int d = 1; d < 64; d <<= 1) { int m = __shfl_up(inc, d); if (tid >= d) inc += m; }
        if (tid < 32) sexcl[tid] = inc - v;
    }
    __syncthreads();

    if (tid < 32) {
        scur[tid] = sexcl[tid];
        int cc = shist[tid];
        if (cc) {
            int fb = (s << 5) + tid;           // absolute final bucket for cursor
            sgof[tid] = atomicAdd(&bcur2[fb], cc) - sexcl[tid];
        }
    }
    __syncthreads();

    if (sba >= 0) {
        int p = atomicAdd(&scur[sba], 1);
        s_sb[p] = sba;
        float4* yr = (float4*)&ys[p * 16];
        yr[0] = ra[0]; yr[1] = ra[1]; yr[2] = ra[2]; yr[3] = ra[3];
    }
    if (sbb >= 0) {
        int p = atomicAdd(&scur[sbb], 1);
        s_sb[p] = sbb;
        float4* yr = (float4*)&ys[p * 16];
        yr[0] = rb[0]; yr[1] = rb[1]; yr[2] = rb[2]; yr[3] = rb[3];
    }
    __syncthreads();

    int fbrel0 = srel << 5;
    for (int i = tid; i < n; i += 512) {
        int sb = s_sb[i];
        int o = sgof[sb] + i;
        if ((unsigned)o < (unsigned)capB) {
            size_t rec = (size_t)(fbrel0 + sb) * capB + o;   // B sweep-relative
            float4* dst = (float4*)(B + rec * 16);
            const float4* sp = (const float4*)&ys[i * 16];
            dst[0] = sp[0]; dst[1] = sp[1]; dst[2] = sp[2]; dst[3] = sp[3];
        }
    }
}

// ---------------- K4: per-bucket counting-sort + register reduction + node MLP ------
__global__ __launch_bounds__(512, 4) void moment_kernel(
    const float* __restrict__ B, const int* __restrict__ bcur2,
    const float* __restrict__ x_s, const float* __restrict__ u,
    const int* __restrict__ batch_s,
    const float* __restrict__ w1b, const float* __restrict__ b1b,
    const float* __restrict__ w2b, const float* __restrict__ b2b,
    float* __restrict__ out, int N, int fb_lo, int capB)
{
    __shared__ float accs[128 * SLOTS];        // 31232 B, plain RMW by owner groups
    __shared__ int   snid[CH4], sidx[CH4];     // 16 KB
    __shared__ int   shist[128], sstart[128], scur[128];
    __shared__ float o1s[128 * 10];
    __shared__ float tw1[810], tw2[100], tb1[16], tb2[16];
    int tid = threadIdx.x;
    int fb = fb_lo + blockIdx.x;
    int node0 = fb << 7;
    if (node0 >= N) return;

    for (int i = tid; i < 810; i += 512) tw1[i] = w1b[i];
    for (int i = tid; i < 100; i += 512) tw2[i] = w2b[i];
    if (tid < 10) { tb1[tid] = b1b[tid]; tb2[tid] = b2b[tid]; }
    for (int i = tid; i < 128 * SLOTS; i += 512) accs[i] = 0.f;
    __syncthreads();

    int cnt_fb = min(bcur2[fb], capB);
    const float* Bb = B + (size_t)(fb - fb_lo) * capB * 16;

    int g = tid >> 4, f = tid & 15;

    for (int e0 = 0; e0 < cnt_fb; e0 += CH4) {
        int m = min(CH4, cnt_fb - e0);

        if (tid < 128) shist[tid] = 0;
        __syncthreads();
        // stage node-ids + chunk histogram
        for (int i = tid; i < m; i += 512) {
            int nid = __float_as_int(Bb[((size_t)(e0 + i)) * 16 + 15]) & 127;
            snid[i] = nid;
            atomicAdd(&shist[nid], 1);
        }
        __syncthreads();
        // scan 128 node counts
        if (tid < 64) {
            int carry = 0;
            for (int base = 0; base < 128; base += 64) {
                int i = base + tid;
                int v = shist[i];
                int inc = v;
#pragma unroll
                for (int d = 1; d < 64; d <<= 1) { int mm = __shfl_up(inc, d); if (tid >= d) inc += mm; }
                sstart[i] = inc - v + carry;
                scur[i]   = inc - v + carry;
                carry += __shfl(inc, 63);
            }
        }
        __syncthreads();
        // scatter indices into node-sorted order
        for (int i = tid; i < m; i += 512) {
            int p = atomicAdd(&scur[snid[i]], 1);
            sidx[p] = i;
        }
        __syncthreads();
        // group walk: 32 groups x 16 lanes; group g owns nodes nd % 32 == g (race-free)
        for (int nd = g; nd < 128; nd += 32) {
            int st = sstart[nd], cnt = shist[nd];
            if (cnt) {
                float s1 = 0.f, s2 = 0.f, s3 = 0.f, s4 = 0.f;
                for (int k = 0; k < cnt; k++) {
                    int e = sidx[st + k];
                    float y = Bb[((size_t)(e0 + e)) * 16 + f];   // L2/L3-hot 64B group read
                    float y2 = y * y;
                    s1 += y; s2 += y2; s3 += y2 * y; s4 += y2 * y2;
                }
                int ab = nd * SLOTS;
                if (f < 15) {
                    accs[ab + f]      += s1;
                    accs[ab + 15 + f] += s2;
                    accs[ab + 30 + f] += s3;
                    accs[ab + 45 + f] += s4;
                } else {
                    accs[ab + 60] += (float)cnt;
                }
            }
        }
        __syncthreads();
    }

    // finalize raw sums -> mean, std, skew, kurt (in place)
    for (int idx = tid; idx < 128 * 16; idx += 512) {
        int ff = idx & 15, nd = idx >> 4;
        if (ff < 15 && node0 + nd < N) {
            int ab = nd * SLOTS;
            float cf  = accs[ab + 60];
            float inv = 1.0f / fmaxf(cf, 1.0f);
            float m1 = accs[ab + ff]      * inv;
            float m2 = accs[ab + 15 + ff] * inv;
            float m3 = accs[ab + 30 + ff] * inv;
            float m4 = accs[ab + 45 + ff] * inv;
            float var = fmaxf(m2 - m1 * m1, 0.0f);
            float sd  = sqrtf(var + 1e-6f);
            float m1sq = m1 * m1;
            float c3 = m3 - 3.0f * m1 * m2 + 2.0f * m1sq * m1;
            float c4 = m4 - 4.0f * m1 * m3 + 6.0f * m1sq * m2 - 3.0f * m1sq * m1sq;
            float is = 1.0f / sd, is2 = is * is;
            accs[ab + ff]      = m1;
            accs[ab + 15 + ff] = sd;
            accs[ab + 30 + ff] = c3 * is2 * is;
            accs[ab + 45 + ff] = c4 * is2 * is2;
        }
    }
    __syncthreads();

    // node MLP layer 1: h[81] -> 10
    for (int idx = tid; idx < 128 * 10; idx += 512) {
        int nd = idx / 10, k = idx - nd * 10;
        int node = node0 + nd;
        if (node >= N) continue;
        int ab = nd * SLOTS;
        float acc = tb1[k];
        const float* xs = x_s + (size_t)node * 10;
#pragma unroll
        for (int j = 0; j < 10; j++) acc = fmaf(xs[j], tw1[j * 10 + k], acc);
        acc = fmaf(accs[ab + 60], tw1[100 + k], acc);
#pragma unroll
        for (int ff = 0; ff < 15; ff++) acc = fmaf(accs[ab + ff],      tw1[(11 + ff) * 10 + k], acc);
#pragma unroll
        for (int ff = 0; ff < 15; ff++) acc = fmaf(accs[ab + 15 + ff], tw1[(26 + ff) * 10 + k], acc);
#pragma unroll
        for (int ff = 0; ff < 15; ff++) acc = fmaf(accs[ab + 30 + ff], tw1[(41 + ff) * 10 + k], acc);
#pragma unroll
        for (int ff = 0; ff < 15; ff++) acc = fmaf(accs[ab + 45 + ff], tw1[(56 + ff) * 10 + k], acc);
        const float* uu = u + (size_t)batch_s[node] * 10;
#pragma unroll
        for (int j = 0; j < 10; j++) acc = fmaf(uu[j], tw1[(71 + j) * 10 + k], acc);
        o1s[idx] = leaky(acc);
    }
    __syncthreads();
    // layer 2 + store
    for (int idx = tid; idx < 128 * 10; idx += 512) {
        int nd = idx / 10, k = idx - nd * 10;
        int node = node0 + nd;
        if (node >= N) continue;
        float acc = tb2[k];
#pragma unroll
        for (int mm = 0; mm < 10; mm++) acc = fmaf(o1s[nd * 10 + mm], tw2[mm * 10 + k], acc);
        out[(size_t)node * 10 + k] = acc;
    }
}

extern "C" void kernel_launch(void* const* d_in, const int* in_sizes, int n_in,
                              void* d_out, int out_size, void* d_ws, size_t ws_size,
                              hipStream_t stream)
{
    const float* x_s       = (const float*)d_in[0];
    const float* x_t       = (const float*)d_in[1];
    const float* edge_attr = (const float*)d_in[2];
    const float* u         = (const float*)d_in[3];
    const int*   edge_index= (const int*)d_in[4];
    const int*   batch_s   = (const int*)d_in[5];
    const float* w1a = (const float*)d_in[6];
    const float* b1a = (const float*)d_in[7];
    const float* w2a = (const float*)d_in[8];
    const float* b2a = (const float*)d_in[9];
    const float* w1b = (const float*)d_in[10];
    const float* b1b = (const float*)d_in[11];
    const float* w2b = (const float*)d_in[12];
    const float* b2b = (const float*)d_in[13];

    int N = in_sizes[0] / 10;   // x_s [N,10]
    int E = in_sizes[2] / 10;   // edge_attr [E,10]
    int NB   = (N + 127) >> 7;          // final 128-node buckets
    int NSUP = (NB + 31) >> 5;          // super-buckets of 4096 nodes

    // capacity estimates (src uniform-random; 8-sigma Poisson guard + slack)
    long epS = ((long)E * 4096 + N - 1) / N;
    long capSl = (epS * 105) / 100 + 16384;
    int capS = (int)(((capSl + C2 - 1) / C2) * C2);     // multiple of C2
    long epB = ((long)E * 128 + N - 1) / N;
    int capB = (int)(epB + 8 * (long)(sqrt((double)epB) + 1.0) + 512);

    // workspace layout
    char* p = (char*)d_ws;
    auto take = [&](size_t bytes) { char* r = p; p += (bytes + 255) & ~(size_t)255; return r; };
    int* acur  = (int*)take((size_t)NSUPMAX * 4);
    int* bcur2 = (int*)take((size_t)NBMAX * 4);
    size_t head  = (size_t)(p - (char*)d_ws);
    size_t avail = (ws_size > head) ? ws_size - head : 0;
    size_t perS  = ((size_t)capS + (size_t)32 * (size_t)capB) * 64;
    int NSsw = (int)(avail / perS);
    if (NSsw < 1) NSsw = 1;
    if (NSsw > NSUP) NSsw = NSUP;
    float* A = (float*)take((size_t)NSsw * (size_t)capS * 64);
    float* B = (float*)take((size_t)NSsw * 32 * (size_t)capB * 64);

    hipMemsetAsync(acur,  0, (size_t)NSUPMAX * 4, stream);
    hipMemsetAsync(bcur2, 0, (size_t)NBMAX * 4, stream);

    int cps = capS / C2;
    int k2grid = (E + C2 - 1) / C2;
    for (int g0 = 0; g0 < NSUP; g0 += NSsw) {
        int g1 = g0 + NSsw; if (g1 > NSUP) g1 = NSUP;
        binmlp_kernel<<<k2grid, 512, 0, stream>>>(
            edge_index, x_t, edge_attr, w1a, b1a, w2a, b2a,
            acur, A, E, g0, g1, capS);
        rebin_kernel<<<(g1 - g0) * cps, 512, 0, stream>>>(
            A, acur, bcur2, B, g0, capS, cps, capB);
        int fb_lo = g0 << 5;
        int fb_hi = g1 << 5; if (fb_hi > NB) fb_hi = NB;
        moment_kernel<<<fb_hi - fb_lo, 512, 0, stream>>>(
            B, bcur2, x_s, u, batch_s,
            w1b, b1b, w2b, b2b, (float*)d_out, N, fb_lo, capB);
    }
}